// Round 14
// baseline (123.531 us; speedup 1.0000x reference)
//
#include <hip/hip_runtime.h>

// Problem constants (reference: B=16384, DIM_X=2048, K=128)
#define BB 16384
#define DD 2048
#define KK 128
#define NT 64            // DD / 32 k-steps
#define RPB 32           // rows per block
#define NBLK 512         // blocks (2 per CU)
#define DELTA 8e-3f      // argmax gap below which we re-resolve in fp64
#define KB 16384         // per-kstep B buffer: E 8KB + D 8KB
#define FCAP 2048        // flag-list capacity (entries of 132 floats)

typedef __attribute__((ext_vector_type(8))) short  bf16x8;
typedef __attribute__((ext_vector_type(4))) float  f32x4;
typedef __attribute__((ext_vector_type(4))) unsigned int u32x4;

union V16 { u32x4 u; f32x4 f; bf16x8 s; };

__device__ __forceinline__ void gld16(const void* g, void* l) {
  __builtin_amdgcn_global_load_lds(
      (const __attribute__((address_space(1))) void*)g,
      (__attribute__((address_space(3))) void*)l, 16, 0, 0);
}

// ---------------------------------------------------------------------------
// Prep (coalesced): RNE-round enc_W and dec_W to bf16, laid out in MFMA
// B-fragment order: element ((t*8+ct)*64+l)*8+j <-> W[ct*16+(l&15)][t*32+(l>>4)*8+j].
// 128 blocks = sel(2) x ct(8) x ktile(8); each stages a 16x256 f32 tile via
// LDS (1KB-contiguous reads, contiguous 16B fragment writes).
// ---------------------------------------------------------------------------
__global__ __launch_bounds__(256) void prep_kernel(
    const float* __restrict__ encW, const float* __restrict__ decW,
    unsigned short* __restrict__ wEh, unsigned short* __restrict__ wDh,
    float* __restrict__ out, unsigned int* __restrict__ counter)
{
  __shared__ float sw[16][260];
  const int bid = blockIdx.x;
  const int tid = threadIdx.x;
  if (bid == 0 && tid == 0) { *counter = 0u; out[2*BB] = 0.f; out[2*BB+1] = 0.f; }
  const int sel = bid >> 6, rem = bid & 63;
  const int ct = rem >> 3, kt = rem & 7;
  const float* W = sel ? decW : encW;
  unsigned short* oh = sel ? wDh : wEh;

  {
    const int row = tid >> 4, seg = tid & 15;
    const float* src = W + (size_t)(ct * 16 + row) * DD + kt * 256 + seg * 16;
#pragma unroll
    for (int i = 0; i < 4; ++i)
      *(f32x4*)&sw[row][seg * 16 + i * 4] = *(const f32x4*)(src + i * 4);
  }
  __syncthreads();

  const int l = tid & 63, wv = tid >> 6;
#pragma unroll
  for (int h = 0; h < 2; ++h) {
    const int tt = wv * 2 + h;
    const int t  = kt * 8 + tt;
    const float* sp = &sw[l & 15][tt * 32 + ((l >> 4) << 3)];
    V16 vh;
#pragma unroll
    for (int p = 0; p < 4; ++p) {
      unsigned hu[2];
#pragma unroll
      for (int q = 0; q < 2; ++q) {
        unsigned u  = __float_as_uint(sp[p * 2 + q]);
        unsigned rh = u + 0x7FFFu + ((u >> 16) & 1u);   // RNE to bf16
        hu[q] = (rh >> 16) & 0xFFFFu;
      }
      vh.u[p] = (hu[1] << 16) | hu[0];
    }
    *(u32x4*)(oh + ((size_t)(t * 8 + ct) * 64 + l) * 8) = vh.u;
  }
}

// ---------------------------------------------------------------------------
// Main: 512 blocks x 512 threads (2 blocks/CU; pool padded to 56320 B so max
// co-residency is exactly 2 -> RA VGPR budget 128, no spills [validated model
// rounds 8-13]). Wave w: wr = w>>2 (16-row group, 2 groups), wcg = w&3
// (32-col group, 2 MFMA tiles). Minimal-traffic decomposition:
//  - A (x): loaded DIRECT global->VGPR in MFMA fragment layout (lane l reads
//    row wr*16+(l&15), k (l>>4)*8..+8: per-row 128B fully coalesced across
//    lanes {l, l+16, l+32, l+48}); x never touches LDS. 1-kstep reg prefetch.
//    bf16 hi/lo split on read (truncation hi + RNE residual; 2-term enc).
//  - B: triple-buffered 16KB/kstep LDS via global_load_lds DMA, issued 2
//    ksteps ahead; reads are dense contiguous 1KB frags (conflict-free).
//  - barrier = s_waitcnt vmcnt(4) (drains DMA(t+1) issued a FULL kstep ago
//    -> zero stall; keeps DMA(t+2)+A(t+1) in flight) + s_barrier.
// Per wave/kstep: 2 gld16 + 2 A-loads + 4 ds_read_b128 + ~14 VALU + 6 MFMA.
// ---------------------------------------------------------------------------
__global__ __launch_bounds__(512)
void main_kernel(
    const float* __restrict__ x, const float* __restrict__ y,
    const float* __restrict__ encb, const float* __restrict__ decb,
    const unsigned short* __restrict__ wEh, const unsigned short* __restrict__ wDh,
    float* __restrict__ out, unsigned int* __restrict__ counter,
    float* __restrict__ list)
{
  __shared__ __align__(16) unsigned char pool[56320];   // occupancy limiter: 2/CU
  const int tid = threadIdx.x;
  const int w = tid >> 6, l = tid & 63;
  const int wr = w >> 2, wcg = w & 3;
  const int rbase = blockIdx.x * RPB;

  // A direct-load pointer (MFMA fragment layout)
  const float* xp = x + (size_t)(rbase + wr * 16 + (l & 15)) * DD + ((l >> 4) << 3);

  // B DMA source/dest: thread t moves bytes t*16 of each 8KB kstep plane
  const unsigned short* gE = wEh + (size_t)tid * 8;
  const unsigned short* gD = wDh + (size_t)tid * 8;
  const int dmadst = w * 1024;          // wave-uniform LDS base (+lane*16 implicit)

  // B read offsets within a buffer
  const int ebo = wcg * 2048 + l * 16;  // E tile pair base
  const int dbo = 8192 + ebo;           // D plane

  f32x4 accE[2], accD[2];
  const f32x4 zero4 = {0.f, 0.f, 0.f, 0.f};
#pragma unroll
  for (int c = 0; c < 2; ++c) { accE[c] = zero4; accD[c] = zero4; }

#define FENCE() asm volatile("" ::: "memory")
  auto DMAB = [&](int nb, int t) {
    gld16(gE + (size_t)t * 4096, pool + nb + dmadst);
    gld16(gD + (size_t)t * 4096, pool + nb + 8192 + dmadst);
  };

#define MFMA(a, b, c) __builtin_amdgcn_mfma_f32_16x16x32_bf16(a, b, c, 0, 0, 0)
#define KSTEP(cb, A0, A1) do {                                                   \
    bf16x8 E0 = *(const bf16x8*)(pool + (cb) + ebo);                             \
    bf16x8 E1 = *(const bf16x8*)(pool + (cb) + ebo + 1024);                      \
    bf16x8 D0 = *(const bf16x8*)(pool + (cb) + dbo);                             \
    bf16x8 D1 = *(const bf16x8*)(pool + (cb) + dbo + 1024);                      \
    float fa[8] = {A0[0],A0[1],A0[2],A0[3],A1[0],A1[1],A1[2],A1[3]};             \
    V16 vh, vl;                                                                  \
    _Pragma("unroll")                                                            \
    for (int p = 0; p < 4; ++p) {                                                \
      unsigned u0 = __float_as_uint(fa[2*p]);                                    \
      unsigned u1 = __float_as_uint(fa[2*p+1]);                                  \
      vh.u[p] = (u0 >> 16) | (u1 & 0xFFFF0000u);                                 \
      float r0 = fa[2*p]   - __uint_as_float(u0 & 0xFFFF0000u);                  \
      float r1 = fa[2*p+1] - __uint_as_float(u1 & 0xFFFF0000u);                  \
      vl.u[p] = (__float_as_uint(r0) >> 16) | (__float_as_uint(r1) & 0xFFFF0000u);\
    }                                                                            \
    bf16x8 ah = vh.s, al = vl.s;                                                 \
    accE[0] = MFMA(ah, E0, accE[0]);                                             \
    accE[1] = MFMA(ah, E1, accE[1]);                                             \
    accD[0] = MFMA(ah, D0, accD[0]);                                             \
    accD[1] = MFMA(ah, D1, accD[1]);                                             \
    accE[0] = MFMA(al, E0, accE[0]);                                             \
    accE[1] = MFMA(al, E1, accE[1]);                                             \
  } while (0)

  int b0 = 0, b1 = KB, b2 = 2 * KB;     // rotating triple buffer
  f32x4 a0, a1, n0, n1;

  // prologue: DMA ksteps 0,1; A regs for kstep 0
  DMAB(b0, 0);
  DMAB(b1, 1);
  FENCE();
  a0 = *(const f32x4*)xp;
  a1 = *(const f32x4*)(xp + 4);
  asm volatile("s_waitcnt vmcnt(4) lgkmcnt(0)" ::: "memory");  // buf0 ready
  __builtin_amdgcn_s_barrier();

  for (int t = 0; t < NT; ++t) {
    if (t + 2 < NT) DMAB(b2, t + 2);    // oldest vmem this kstep
    FENCE();
    if (t + 1 < NT) {
      const float* p = xp + (size_t)(t + 1) * 32;
      n0 = *(const f32x4*)p;
      n1 = *(const f32x4*)(p + 4);
    }
    __builtin_amdgcn_s_setprio(1);
    KSTEP(b0, a0, a1);
    __builtin_amdgcn_s_setprio(0);
    if (t + 1 < NT) { a0 = n0; a1 = n1; }
    // drain DMA(t+1) (a full kstep old -> no stall); keep DMA(t+2)+A(t+1)
    if (t + 2 < NT)
      asm volatile("s_waitcnt vmcnt(4) lgkmcnt(0)" ::: "memory");
    else if (t + 1 < NT)
      asm volatile("s_waitcnt vmcnt(2) lgkmcnt(0)" ::: "memory");
    else
      asm volatile("s_waitcnt vmcnt(0) lgkmcnt(0)" ::: "memory");
    __builtin_amdgcn_s_barrier();
    int tmp = b0; b0 = b1; b1 = b2; b2 = tmp;
  }
#undef KSTEP
#undef MFMA
#undef FENCE

  // ---------------- epilogue (overlays the staging pool) ----------------
  float* sT  = (float*)pool;                  // [32][132] dec-GEMM results
  float* sS  = (float*)(pool + 16896);        // [32][128] enc s-values (biased)
  float* sm1 = (float*)(pool + 33280);        // [32][4] top-1
  float* sm2 = (float*)(pool + 33792);        // [32][4] top-2
  int*   si1 = (int*)  (pool + 34304);        // [32][4] argmax col

  {
    const int q = l >> 4, cc = l & 15;
    const int col0 = wcg * 32 + cc;
    const int col1 = col0 + 16;
#pragma unroll
    for (int c = 0; c < 2; ++c) {
      const int col = wcg * 32 + c * 16 + cc;
#pragma unroll
      for (int i = 0; i < 4; ++i)
        sT[(wr * 16 + q * 4 + i) * 132 + col] = accD[c][i];
    }
    const float bi0 = encb[col0], bi1 = encb[col1];
    float m1v[4], m2v[4]; int i1v[4];
#pragma unroll
    for (int i = 0; i < 4; ++i) {
      const int row = wr * 16 + q * 4 + i;
      float v0 = accE[0][i] + bi0;
      float v1 = accE[1][i] + bi1;
      sS[row * 128 + col0] = v0;
      sS[row * 128 + col1] = v1;
      if (v0 >= v1) { m1v[i] = v0; m2v[i] = v1; i1v[i] = col0; }
      else          { m1v[i] = v1; m2v[i] = v0; i1v[i] = col1; }
    }
#pragma unroll
    for (int d = 1; d < 16; d <<= 1) {
#pragma unroll
      for (int i = 0; i < 4; ++i) {
        float om1 = __shfl_xor(m1v[i], d);
        float om2 = __shfl_xor(m2v[i], d);
        int   oi  = __shfl_xor(i1v[i], d);
        if (om1 > m1v[i] || (om1 == m1v[i] && oi < i1v[i])) {
          m2v[i] = fmaxf(m1v[i], om2); m1v[i] = om1; i1v[i] = oi;
        } else {
          m2v[i] = fmaxf(m2v[i], om1);
        }
      }
    }
    if (cc == 0) {
#pragma unroll
      for (int i = 0; i < 4; ++i) {
        const int row = wr * 16 + q * 4 + i;
        sm1[row * 4 + wcg] = m1v[i];
        sm2[row * 4 + wcg] = m2v[i];
        si1[row * 4 + wcg] = i1v[i];
      }
    }
  }
  __syncthreads();

  float lossAcc = 0.f, accAcc = 0.f;
  if (tid < RPB) {
    const int row = tid, R = rbase + row;
    float m1 = -3.4e38f, m2 = -3.4e38f; int i1 = 0;
#pragma unroll
    for (int g = 0; g < 4; ++g) {
      float a1g = sm1[row * 4 + g], a2g = sm2[row * 4 + g];
      int ai = si1[row * 4 + g];
      if (a1g > m1) { m2 = fmaxf(m1, a2g); m1 = a1g; i1 = ai; }
      else          { m2 = fmaxf(m2, a1g); }
    }
    float yh = sT[row * 132 + i1] + decb[i1];
    out[R]      = yh;
    out[BB + R] = (float)i1;
    if (m1 - m2 < DELTA) {                     // near-tie: fp64 re-resolve later
      unsigned p = atomicAdd(counter, 1u);
      if (p < (unsigned)FCAP) {
        float* ent = list + (size_t)p * 132;
        ((unsigned*)ent)[0] = (unsigned)R;
        const f32x4* sr = (const f32x4*)(sS + row * 128);
        f32x4* dst = (f32x4*)(ent + 4);
#pragma unroll
        for (int j = 0; j < 32; ++j) dst[j] = sr[j];
      }
    }
    float yv = y[R];
    float d  = yh - yv;
    lossAcc = d * d;
    float sg = (yh > 0.f) ? 1.f : ((yh < 0.f) ? -1.f : 0.f);
    accAcc = (sg == yv) ? 1.f : 0.f;
  }
#pragma unroll
  for (int d = 1; d < 64; d <<= 1) {
    lossAcc += __shfl_xor(lossAcc, d);
    accAcc  += __shfl_xor(accAcc, d);
  }
  if (tid == 0) {
    atomicAdd(&out[2*BB],     lossAcc * (1.f / BB));
    atomicAdd(&out[2*BB + 1], accAcc  * (1.f / BB));
  }
}

// ---------------------------------------------------------------------------
// Fixup v2: one wave per flagged row. Reads the dumped approx s-row, selects
// candidate cols within (m1 - 2*DELTA), recomputes ONLY those (typically 1-3)
// in fp64 (coalesced 1KB loads), picks the true argmax, recomputes y_hat in
// fp64, patches out + loss/accuracy atomics.
// ---------------------------------------------------------------------------
__global__ __launch_bounds__(64) void fixup_kernel(
    const float* __restrict__ x, const float* __restrict__ y,
    const float* __restrict__ encW, const float* __restrict__ encb,
    const float* __restrict__ decW, const float* __restrict__ decb,
    float* __restrict__ out,
    const unsigned int* __restrict__ counter, const float* __restrict__ list)
{
  int n = (int)*counter;
  if (n > FCAP) n = FCAP;
  const int l = threadIdx.x;
  for (int e = blockIdx.x; e < n; e += gridDim.x) {
    const float* ent = list + (size_t)e * 132;
    const int R = (int)((const unsigned*)ent)[0];
    const float s0 = ent[4 + 2 * l], s1 = ent[5 + 2 * l];
    float m = fmaxf(s0, s1);
#pragma unroll
    for (int d = 1; d < 64; d <<= 1) m = fmaxf(m, __shfl_xor(m, d));
    const float win = m - 2.0f * DELTA;
    unsigned long long mm0 = __ballot(s0 >= win);
    unsigned long long mm1 = __ballot(s1 >= win);
    const float* xr = x + (size_t)R * DD;
    double best = -1e300; int bk = KK;
    while (mm0 | mm1) {
      int c;
      if (mm0) { int b = __builtin_ctzll(mm0); mm0 &= mm0 - 1; c = 2 * b; }
      else     { int b = __builtin_ctzll(mm1); mm1 &= mm1 - 1; c = 2 * b + 1; }
      const float* wp = encW + (size_t)c * DD;
      double s = 0.0;
#pragma unroll
      for (int j = 0; j < 8; ++j) {
        f32x4 wv = *(const f32x4*)(wp + j * 256 + l * 4);
        f32x4 xv = *(const f32x4*)(xr + j * 256 + l * 4);
        s = fma((double)xv[0], (double)wv[0], s);
        s = fma((double)xv[1], (double)wv[1], s);
        s = fma((double)xv[2], (double)wv[2], s);
        s = fma((double)xv[3], (double)wv[3], s);
      }
#pragma unroll
      for (int d = 1; d < 64; d <<= 1) s += __shfl_xor(s, d);
      s += (double)encb[c];
      if (s > best || (s == best && c < bk)) { best = s; bk = c; }
    }
    // dec dot in fp64
    const float* dr = decW + (size_t)bk * DD;
    double t = 0.0;
#pragma unroll
    for (int j = 0; j < 8; ++j) {
      f32x4 wv = *(const f32x4*)(dr + j * 256 + l * 4);
      f32x4 xv = *(const f32x4*)(xr + j * 256 + l * 4);
      t = fma((double)xv[0], (double)wv[0], t);
      t = fma((double)xv[1], (double)wv[1], t);
      t = fma((double)xv[2], (double)wv[2], t);
      t = fma((double)xv[3], (double)wv[3], t);
    }
#pragma unroll
    for (int d = 1; d < 64; d <<= 1) t += __shfl_xor(t, d);
    if (l == 0) {
      float yh = (float)(t + (double)decb[bk]);
      float yv = y[R];
      float old = out[R];
      float dn = yh - yv, dol = old - yv;
      atomicAdd(&out[2*BB], (dn*dn - dol*dol) * (1.f / BB));
      float sgn = (yh  > 0.f) ? 1.f : ((yh  < 0.f) ? -1.f : 0.f);
      float sgo = (old > 0.f) ? 1.f : ((old < 0.f) ? -1.f : 0.f);
      float mn = (sgn == yv) ? 1.f : 0.f;
      float mo = (sgo == yv) ? 1.f : 0.f;
      atomicAdd(&out[2*BB + 1], (mn - mo) * (1.f / BB));
      out[R]      = yh;
      out[BB + R] = (float)bk;
    }
  }
}

extern "C" void kernel_launch(void* const* d_in, const int* in_sizes, int n_in,
                              void* d_out, int out_size, void* d_ws, size_t ws_size,
                              hipStream_t stream)
{
  const float* x    = (const float*)d_in[0];
  const float* y    = (const float*)d_in[1];
  // d_in[2] = z (unused by the reference computation)
  const float* encW = (const float*)d_in[3];
  const float* encb = (const float*)d_in[4];
  const float* decW = (const float*)d_in[5];   // [1,128,2048] -> row-major [128][2048]
  const float* decb = (const float*)d_in[6];
  float* out = (float*)d_out;

  unsigned char* ws = (unsigned char*)d_ws;
  unsigned short* wEh = (unsigned short*)ws;                 // 512 KB
  unsigned short* wDh = (unsigned short*)(ws + 524288);      // 512 KB
  unsigned int* counter = (unsigned int*)(ws + 1048576);
  float* list = (float*)(ws + 1048592);                      // FCAP x 132 floats

  prep_kernel<<<128, 256, 0, stream>>>(encW, decW, wEh, wDh, out, counter);
  main_kernel<<<NBLK, 512, 0, stream>>>(x, y, encb, decb, wEh, wDh,
                                        out, counter, list);
  fixup_kernel<<<512, 64, 0, stream>>>(x, y, encW, encb, decW, decb,
                                       out, counter, list);
}

// Round 15
// 89.072 us; speedup vs baseline: 1.3869x; 1.3869x over previous
//
#include <hip/hip_runtime.h>

// Problem constants (reference: B=16384, DIM_X=2048, K=128)
#define BB 16384
#define DD 2048
#define KK 128
#define NT 64            // DD / 32 k-steps
#define NCHK 16          // chunks of 4 k-steps
#define RPB 32           // rows per block
#define NBLK 512         // blocks
#define DELTA 8e-3f      // argmax gap below which we re-resolve in fp64
#define CHB 16384        // chunk buffer: hi 8KB + lo 8KB
#define FCAP 2048        // flag-list capacity (entries of 132 floats)

typedef __attribute__((ext_vector_type(8))) short  bf16x8;
typedef __attribute__((ext_vector_type(4))) float  f32x4;
typedef __attribute__((ext_vector_type(4))) unsigned int u32x4;

union V16 { u32x4 u; f32x4 f; bf16x8 s; };

// barrier WITHOUT vmcnt drain: LDS ops drained (lgkmcnt); register-destined
// global loads (B fragments, x prefetch) are waited by the compiler at uses.
__device__ __forceinline__ void wg_barrier() {
  asm volatile("s_waitcnt lgkmcnt(0)\n\ts_barrier" ::: "memory");
}

// ---------------------------------------------------------------------------
// Prep (coalesced): RNE-round enc_W and dec_W to bf16, laid out in MFMA
// B-fragment order: element ((t*8+ct)*64+l)*8+j <-> W[ct*16+(l&15)][t*32+(l>>4)*8+j].
// 128 blocks = sel(2) x ct(8) x ktile(8); each stages a 16x256 f32 tile via
// LDS (1KB-contiguous reads, contiguous 16B fragment writes).
// ---------------------------------------------------------------------------
__global__ __launch_bounds__(256) void prep_kernel(
    const float* __restrict__ encW, const float* __restrict__ decW,
    unsigned short* __restrict__ wEh, unsigned short* __restrict__ wDh,
    float* __restrict__ out, unsigned int* __restrict__ counter)
{
  __shared__ float sw[16][260];
  const int bid = blockIdx.x;
  const int tid = threadIdx.x;
  if (bid == 0 && tid == 0) { *counter = 0u; out[2*BB] = 0.f; out[2*BB+1] = 0.f; }
  const int sel = bid >> 6, rem = bid & 63;
  const int ct = rem >> 3, kt = rem & 7;
  const float* W = sel ? decW : encW;
  unsigned short* oh = sel ? wDh : wEh;

  {
    const int row = tid >> 4, seg = tid & 15;
    const float* src = W + (size_t)(ct * 16 + row) * DD + kt * 256 + seg * 16;
#pragma unroll
    for (int i = 0; i < 4; ++i)
      *(f32x4*)&sw[row][seg * 16 + i * 4] = *(const f32x4*)(src + i * 4);
  }
  __syncthreads();

  const int l = tid & 63, wv = tid >> 6;
#pragma unroll
  for (int h = 0; h < 2; ++h) {
    const int tt = wv * 2 + h;
    const int t  = kt * 8 + tt;
    const float* sp = &sw[l & 15][tt * 32 + ((l >> 4) << 3)];
    V16 vh;
#pragma unroll
    for (int p = 0; p < 4; ++p) {
      unsigned hu[2];
#pragma unroll
      for (int q = 0; q < 2; ++q) {
        unsigned u  = __float_as_uint(sp[p * 2 + q]);
        unsigned rh = u + 0x7FFFu + ((u >> 16) & 1u);   // RNE to bf16
        hu[q] = (rh >> 16) & 0xFFFFu;
      }
      vh.u[p] = (hu[1] << 16) | hu[0];
    }
    *(u32x4*)(oh + ((size_t)(t * 8 + ct) * 64 + l) * 8) = vh.u;
  }
}

// ---------------------------------------------------------------------------
// Main: 512 blocks x 512 threads. pool padded to 46080 B -> exactly 3 blocks/CU
// by LDS (threads allow 4) -> 24 waves/CU = 6 waves/SIMD (the latency-hiding
// lever: R11/R13 ran 4/SIMD at 76/95us; R12 2/SIMD at 82us) -> RA VGPR budget
// ~84, live set ~70 fits (validated budget model rounds 8-14).
// Wave w (8 waves) = 32 rows x 16 cols (rt=2, ct=1): per-kstep per-wave
// 4 ds_read_b128 (A hi/lo for 2 row-tiles) + 2 B loads (E,D; 16 VGPR
// double-set) + 6 MFMA. x split bf16 hi/lo ONCE at stage (each thread: 8
// floats -> one 16B hi + one 16B lo write, block-swizzled kseg^(row&15)) --
// zero split-VALU in the K-loop. B prefetched 1 kstep ahead; x 1 chunk ahead;
// 16 lgkm-only barriers (B/x reg-loads flow across).
// ---------------------------------------------------------------------------
__global__ __launch_bounds__(512)
void main_kernel(
    const float* __restrict__ x, const float* __restrict__ y,
    const float* __restrict__ encb, const float* __restrict__ decb,
    const unsigned short* __restrict__ wEh, const unsigned short* __restrict__ wDh,
    float* __restrict__ out, unsigned int* __restrict__ counter,
    float* __restrict__ list)
{
  __shared__ __align__(16) unsigned char pool[46080];   // 3 blocks/CU limiter
  const int tid = threadIdx.x;
  const int w = tid >> 6, l = tid & 63;
  const int rbase = blockIdx.x * RPB;

  // x stage: thread -> (row = tid>>4, kseg = tid&15), 8 consecutive floats
  const int srow = tid >> 4, kseg = tid & 15;
  const float* gXc = x + (size_t)(rbase + srow) * DD + kseg * 8;
  const int woff = srow * 256 + ((kseg ^ (srow & 15)) << 4);

  // B fragment sources; wave w owns col-tile w (16 cols)
  const unsigned short* gE = wEh + (size_t)(w * 64 + l) * 8;
  const unsigned short* gD = wDh + (size_t)(w * 64 + l) * 8;

  // A-fragment LDS offsets (row-tile rt in {0,1}; swizzle key = l&15 = row&15)
  const int rowb0 = (l & 15) * 256;
  const int rowb1 = (16 + (l & 15)) * 256;
  int blkb[4];
#pragma unroll
  for (int tt = 0; tt < 4; ++tt)
    blkb[tt] = ((tt * 4 + (l >> 4)) ^ (l & 15)) << 4;

  f32x4 accE[2], accD[2];
  const f32x4 zero4 = {0.f, 0.f, 0.f, 0.f};
#pragma unroll
  for (int rt = 0; rt < 2; ++rt) { accE[rt] = zero4; accD[rt] = zero4; }

  auto WRX = [&](int nb, f32x4 A, f32x4 Bv) {
    float fa[8] = {A[0],A[1],A[2],A[3],Bv[0],Bv[1],Bv[2],Bv[3]};
    V16 vh, vl;
#pragma unroll
    for (int p = 0; p < 4; ++p) {
      unsigned u0 = __float_as_uint(fa[2*p]);
      unsigned u1 = __float_as_uint(fa[2*p+1]);
      vh.u[p] = (u0 >> 16) | (u1 & 0xFFFF0000u);
      float r0 = fa[2*p]   - __uint_as_float(u0 & 0xFFFF0000u);
      float r1 = fa[2*p+1] - __uint_as_float(u1 & 0xFFFF0000u);
      vl.u[p] = (__float_as_uint(r0) >> 16) | (__float_as_uint(r1) & 0xFFFF0000u);
    }
    unsigned char* bp = pool + nb + woff;
    *(u32x4*)bp           = vh.u;
    *(u32x4*)(bp + 8192)  = vl.u;
  };

#define LDB(base, t) (*(const bf16x8*)((base) + (size_t)((t) > 63 ? 63 : (t)) * 4096))
#define MFMA(a, b, c) __builtin_amdgcn_mfma_f32_16x16x32_bf16(a, b, c, 0, 0, 0)
#define KSTEP(cbase, tt, E, D) do {                                              \
    const unsigned char* bp = pool + (cbase);                                    \
    bf16x8 ah0 = *(const bf16x8*)(bp + rowb0 + blkb[tt]);                        \
    bf16x8 al0 = *(const bf16x8*)(bp + rowb0 + blkb[tt] + 8192);                 \
    bf16x8 ah1 = *(const bf16x8*)(bp + rowb1 + blkb[tt]);                        \
    bf16x8 al1 = *(const bf16x8*)(bp + rowb1 + blkb[tt] + 8192);                 \
    accE[0] = MFMA(ah0, E, accE[0]);                                             \
    accE[1] = MFMA(ah1, E, accE[1]);                                             \
    accD[0] = MFMA(ah0, D, accD[0]);                                             \
    accD[1] = MFMA(ah1, D, accD[1]);                                             \
    accE[0] = MFMA(al0, E, accE[0]);                                             \
    accE[1] = MFMA(al1, E, accE[1]);                                             \
  } while (0)

  bf16x8 E0, D0, E1, D1;     // double-set B (2 frags each)
  f32x4 xA, xB;

  // prologue: chunk 0 x -> buffer 0; B kstep 0 -> set0
  xA = *(const f32x4*)gXc; xB = *(const f32x4*)(gXc + 4);
  E0 = LDB(gE, 0); D0 = LDB(gD, 0);
  WRX(0, xA, xB);
  wg_barrier();

  for (int c = 0; c < NCHK; ++c) {
    const int cb = (c & 1) * CHB;
    const int nb = cb ^ CHB;
    if (c + 1 < NCHK) {
      const float* p = gXc + (size_t)(c + 1) * 128;
      xA = *(const f32x4*)p; xB = *(const f32x4*)(p + 4);
    }
    E1 = LDB(gE, 4*c + 1); D1 = LDB(gD, 4*c + 1);
    __builtin_amdgcn_s_setprio(1);
    KSTEP(cb, 0, E0, D0);
    __builtin_amdgcn_s_setprio(0);
    E0 = LDB(gE, 4*c + 2); D0 = LDB(gD, 4*c + 2);
    __builtin_amdgcn_s_setprio(1);
    KSTEP(cb, 1, E1, D1);
    __builtin_amdgcn_s_setprio(0);
    E1 = LDB(gE, 4*c + 3); D1 = LDB(gD, 4*c + 3);
    __builtin_amdgcn_s_setprio(1);
    KSTEP(cb, 2, E0, D0);
    __builtin_amdgcn_s_setprio(0);
    E0 = LDB(gE, 4*c + 4); D0 = LDB(gD, 4*c + 4);   // next chunk kstep0 (clamped)
    __builtin_amdgcn_s_setprio(1);
    KSTEP(cb, 3, E1, D1);
    __builtin_amdgcn_s_setprio(0);
    if (c + 1 < NCHK) WRX(nb, xA, xB);   // x latency hidden by this chunk
    wg_barrier();
  }
#undef KSTEP
#undef MFMA
#undef LDB

  // ---------------- epilogue (overlays the staging pool) ----------------
  float* sT  = (float*)pool;                  // [32][132] dec-GEMM results
  float* sS  = (float*)(pool + 16896);        // [32][128] enc s-values (biased)
  float* sm1 = (float*)(pool + 33280);        // [32][8] top-1
  float* sm2 = (float*)(pool + 34304);        // [32][8] top-2
  int*   si1 = (int*)  (pool + 35328);        // [32][8] argmax col

  {
    const int q = l >> 4, cc = l & 15;
    const int col = w * 16 + cc;
    const float bias = encb[col];
    float m1v[8], m2v[8]; int i1v[8];
#pragma unroll
    for (int rt = 0; rt < 2; ++rt)
#pragma unroll
      for (int i = 0; i < 4; ++i) {
        const int j = rt * 4 + i;
        const int row = rt * 16 + q * 4 + i;
        sT[row * 132 + col] = accD[rt][i];
        float v = accE[rt][i] + bias;
        sS[row * 128 + col] = v;
        m1v[j] = v; m2v[j] = -3.4e38f; i1v[j] = col;
      }
#pragma unroll
    for (int d = 1; d < 16; d <<= 1) {
#pragma unroll
      for (int j = 0; j < 8; ++j) {
        float om1 = __shfl_xor(m1v[j], d);
        float om2 = __shfl_xor(m2v[j], d);
        int   oi  = __shfl_xor(i1v[j], d);
        if (om1 > m1v[j] || (om1 == m1v[j] && oi < i1v[j])) {
          m2v[j] = fmaxf(m1v[j], om2); m1v[j] = om1; i1v[j] = oi;
        } else {
          m2v[j] = fmaxf(m2v[j], om1);
        }
      }
    }
    if (cc == 0) {
#pragma unroll
      for (int rt = 0; rt < 2; ++rt)
#pragma unroll
        for (int i = 0; i < 4; ++i) {
          const int j = rt * 4 + i;
          const int row = rt * 16 + q * 4 + i;
          sm1[row * 8 + w] = m1v[j];
          sm2[row * 8 + w] = m2v[j];
          si1[row * 8 + w] = i1v[j];
        }
    }
  }
  __syncthreads();

  float lossAcc = 0.f, accAcc = 0.f;
  if (tid < RPB) {
    const int row = tid, R = rbase + row;
    float m1 = -3.4e38f, m2 = -3.4e38f; int i1 = 0;
#pragma unroll
    for (int g = 0; g < 8; ++g) {
      float a1g = sm1[row * 8 + g], a2g = sm2[row * 8 + g];
      int ai = si1[row * 8 + g];
      if (a1g > m1) { m2 = fmaxf(m1, a2g); m1 = a1g; i1 = ai; }
      else          { m2 = fmaxf(m2, a1g); }
    }
    float yh = sT[row * 132 + i1] + decb[i1];
    out[R]      = yh;
    out[BB + R] = (float)i1;
    if (m1 - m2 < DELTA) {                     // near-tie: fp64 re-resolve later
      unsigned p = atomicAdd(counter, 1u);
      if (p < (unsigned)FCAP) {
        float* ent = list + (size_t)p * 132;
        ((unsigned*)ent)[0] = (unsigned)R;
        const f32x4* sr = (const f32x4*)(sS + row * 128);
        f32x4* dst = (f32x4*)(ent + 4);
#pragma unroll
        for (int j = 0; j < 32; ++j) dst[j] = sr[j];
      }
    }
    float yv = y[R];
    float d  = yh - yv;
    lossAcc = d * d;
    float sg = (yh > 0.f) ? 1.f : ((yh < 0.f) ? -1.f : 0.f);
    accAcc = (sg == yv) ? 1.f : 0.f;
  }
#pragma unroll
  for (int d = 1; d < 64; d <<= 1) {
    lossAcc += __shfl_xor(lossAcc, d);
    accAcc  += __shfl_xor(accAcc, d);
  }
  if (tid == 0) {
    atomicAdd(&out[2*BB],     lossAcc * (1.f / BB));
    atomicAdd(&out[2*BB + 1], accAcc  * (1.f / BB));
  }
}

// ---------------------------------------------------------------------------
// Fixup v2: one wave per flagged row. Reads the dumped approx s-row, selects
// candidate cols within (m1 - 2*DELTA), recomputes ONLY those (typically 1-3)
// in fp64 (coalesced 1KB loads), picks the true argmax, recomputes y_hat in
// fp64, patches out + loss/accuracy atomics.
// ---------------------------------------------------------------------------
__global__ __launch_bounds__(64) void fixup_kernel(
    const float* __restrict__ x, const float* __restrict__ y,
    const float* __restrict__ encW, const float* __restrict__ encb,
    const float* __restrict__ decW, const float* __restrict__ decb,
    float* __restrict__ out,
    const unsigned int* __restrict__ counter, const float* __restrict__ list)
{
  int n = (int)*counter;
  if (n > FCAP) n = FCAP;
  const int l = threadIdx.x;
  for (int e = blockIdx.x; e < n; e += gridDim.x) {
    const float* ent = list + (size_t)e * 132;
    const int R = (int)((const unsigned*)ent)[0];
    const float s0 = ent[4 + 2 * l], s1 = ent[5 + 2 * l];
    float m = fmaxf(s0, s1);
#pragma unroll
    for (int d = 1; d < 64; d <<= 1) m = fmaxf(m, __shfl_xor(m, d));
    const float win = m - 2.0f * DELTA;
    unsigned long long mm0 = __ballot(s0 >= win);
    unsigned long long mm1 = __ballot(s1 >= win);
    const float* xr = x + (size_t)R * DD;
    double best = -1e300; int bk = KK;
    while (mm0 | mm1) {
      int c;
      if (mm0) { int b = __builtin_ctzll(mm0); mm0 &= mm0 - 1; c = 2 * b; }
      else     { int b = __builtin_ctzll(mm1); mm1 &= mm1 - 1; c = 2 * b + 1; }
      const float* wp = encW + (size_t)c * DD;
      double s = 0.0;
#pragma unroll
      for (int j = 0; j < 8; ++j) {
        f32x4 wv = *(const f32x4*)(wp + j * 256 + l * 4);
        f32x4 xv = *(const f32x4*)(xr + j * 256 + l * 4);
        s = fma((double)xv[0], (double)wv[0], s);
        s = fma((double)xv[1], (double)wv[1], s);
        s = fma((double)xv[2], (double)wv[2], s);
        s = fma((double)xv[3], (double)wv[3], s);
      }
#pragma unroll
      for (int d = 1; d < 64; d <<= 1) s += __shfl_xor(s, d);
      s += (double)encb[c];
      if (s > best || (s == best && c < bk)) { best = s; bk = c; }
    }
    // dec dot in fp64
    const float* dr = decW + (size_t)bk * DD;
    double t = 0.0;
#pragma unroll
    for (int j = 0; j < 8; ++j) {
      f32x4 wv = *(const f32x4*)(dr + j * 256 + l * 4);
      f32x4 xv = *(const f32x4*)(xr + j * 256 + l * 4);
      t = fma((double)xv[0], (double)wv[0], t);
      t = fma((double)xv[1], (double)wv[1], t);
      t = fma((double)xv[2], (double)wv[2], t);
      t = fma((double)xv[3], (double)wv[3], t);
    }
#pragma unroll
    for (int d = 1; d < 64; d <<= 1) t += __shfl_xor(t, d);
    if (l == 0) {
      float yh = (float)(t + (double)decb[bk]);
      float yv = y[R];
      float old = out[R];
      float dn = yh - yv, dol = old - yv;
      atomicAdd(&out[2*BB], (dn*dn - dol*dol) * (1.f / BB));
      float sgn = (yh  > 0.f) ? 1.f : ((yh  < 0.f) ? -1.f : 0.f);
      float sgo = (old > 0.f) ? 1.f : ((old < 0.f) ? -1.f : 0.f);
      float mn = (sgn == yv) ? 1.f : 0.f;
      float mo = (sgo == yv) ? 1.f : 0.f;
      atomicAdd(&out[2*BB + 1], (mn - mo) * (1.f / BB));
      out[R]      = yh;
      out[BB + R] = (float)bk;
    }
  }
}

extern "C" void kernel_launch(void* const* d_in, const int* in_sizes, int n_in,
                              void* d_out, int out_size, void* d_ws, size_t ws_size,
                              hipStream_t stream)
{
  const float* x    = (const float*)d_in[0];
  const float* y    = (const float*)d_in[1];
  // d_in[2] = z (unused by the reference computation)
  const float* encW = (const float*)d_in[3];
  const float* encb = (const float*)d_in[4];
  const float* decW = (const float*)d_in[5];   // [1,128,2048] -> row-major [128][2048]
  const float* decb = (const float*)d_in[6];
  float* out = (float*)d_out;

  unsigned char* ws = (unsigned char*)d_ws;
  unsigned short* wEh = (unsigned short*)ws;                 // 512 KB
  unsigned short* wDh = (unsigned short*)(ws + 524288);      // 512 KB
  unsigned int* counter = (unsigned int*)(ws + 1048576);
  float* list = (float*)(ws + 1048592);                      // FCAP x 132 floats

  prep_kernel<<<128, 256, 0, stream>>>(encW, decW, wEh, wDh, out, counter);
  main_kernel<<<NBLK, 512, 0, stream>>>(x, y, encb, decb, wEh, wDh,
                                        out, counter, list);
  fixup_kernel<<<512, 64, 0, stream>>>(x, y, encW, encb, decW, decb,
                                       out, counter, list);
}

// Round 16
// 88.326 us; speedup vs baseline: 1.3986x; 1.0085x over previous
//
#include <hip/hip_runtime.h>

// Problem constants (reference: B=16384, DIM_X=2048, K=128)
#define BB 16384
#define DD 2048
#define KK 128
#define NT 64            // DD / 32 k-steps
#define RPB 64           // rows per block
#define NBLK 256         // blocks
#define DELTA 8e-3f      // argmax gap below which we re-resolve in fp64
#define BUFS 26624       // per-kstep buffer: xhi 5K | xlo 5K | E 8K | D 8K
#define FCAP 2048        // flag-list capacity (entries of 132 floats)

typedef __attribute__((ext_vector_type(8))) short  bf16x8;
typedef __attribute__((ext_vector_type(4))) float  f32x4;
typedef __attribute__((ext_vector_type(4))) unsigned int u32x4;
typedef __attribute__((ext_vector_type(2))) unsigned int u32x2;

union V16 { u32x4 u; f32x4 f; bf16x8 s; };

__device__ __forceinline__ void gld16(const void* g, void* l) {
  __builtin_amdgcn_global_load_lds(
      (const __attribute__((address_space(1))) void*)g,
      (__attribute__((address_space(3))) void*)l, 16, 0, 0);
}

// ---------------------------------------------------------------------------
// Prep (coalesced): RNE-round enc_W and dec_W to bf16, laid out in MFMA
// B-fragment order: element ((t*8+ct)*64+l)*8+j <-> W[ct*16+(l&15)][t*32+(l>>4)*8+j].
// 128 blocks = sel(2) x ct(8) x ktile(8); each stages a 16x256 f32 tile via
// LDS (1KB-contiguous reads, contiguous 16B fragment writes).
// ---------------------------------------------------------------------------
__global__ __launch_bounds__(256) void prep_kernel(
    const float* __restrict__ encW, const float* __restrict__ decW,
    unsigned short* __restrict__ wEh, unsigned short* __restrict__ wDh,
    float* __restrict__ out, unsigned int* __restrict__ counter)
{
  __shared__ float sw[16][260];
  const int bid = blockIdx.x;
  const int tid = threadIdx.x;
  if (bid == 0 && tid == 0) { *counter = 0u; out[2*BB] = 0.f; out[2*BB+1] = 0.f; }
  const int sel = bid >> 6, rem = bid & 63;
  const int ct = rem >> 3, kt = rem & 7;
  const float* W = sel ? decW : encW;
  unsigned short* oh = sel ? wDh : wEh;

  {
    const int row = tid >> 4, seg = tid & 15;
    const float* src = W + (size_t)(ct * 16 + row) * DD + kt * 256 + seg * 16;
#pragma unroll
    for (int i = 0; i < 4; ++i)
      *(f32x4*)&sw[row][seg * 16 + i * 4] = *(const f32x4*)(src + i * 4);
  }
  __syncthreads();

  const int l = tid & 63, wv = tid >> 6;
#pragma unroll
  for (int h = 0; h < 2; ++h) {
    const int tt = wv * 2 + h;
    const int t  = kt * 8 + tt;
    const float* sp = &sw[l & 15][tt * 32 + ((l >> 4) << 3)];
    V16 vh;
#pragma unroll
    for (int p = 0; p < 4; ++p) {
      unsigned hu[2];
#pragma unroll
      for (int q = 0; q < 2; ++q) {
        unsigned u  = __float_as_uint(sp[p * 2 + q]);
        unsigned rh = u + 0x7FFFu + ((u >> 16) & 1u);   // RNE to bf16
        hu[q] = (rh >> 16) & 0xFFFFu;
      }
      vh.u[p] = (hu[1] << 16) | hu[0];
    }
    *(u32x4*)(oh + ((size_t)(t * 8 + ct) * 64 + l) * 8) = vh.u;
  }
}

// ---------------------------------------------------------------------------
// Main: 256 blocks x 512 threads, pool=70656 B -> EXACTLY 2 blocks/CU (16
// waves/CU = 4/SIMD, 128-VGPR budget; validated model R8-R15). R12's
// minimal-traffic all-LDS operand path at double the co-residency:
//  - wave w: wr=w>>2 (2 row-groups of 32), wcg=w&3 (4 col-groups, 2 tiles).
//  - x: split bf16 hi/lo ONCE at stage into 80B-stride rows (stride 5x16B:
//    8B writes AND b128 reads both land 2 lanes/bank = free, no XOR needed).
//  - B: 16KB/kstep DMA'd to LDS via 2 gld16/thread, issued ONE FULL KSTEP
//    ahead (~1400cy >> L2 latency); dense 1KB frag reads.
//  - per-kstep barrier: vmcnt(0) retires only the kstep-old DMA (no stall),
//    lgkmcnt(0) covers ds writes.
// Per wave/kstep: 4 A ds_read_b128 + 4 B ds_read_b128 + 12 MFMA
// (enc 2-term x 2 tiles x 2 rt = 8; dec 1-term = 4).
// ---------------------------------------------------------------------------
__global__ __launch_bounds__(512)
void main_kernel(
    const float* __restrict__ x, const float* __restrict__ y,
    const float* __restrict__ encb, const float* __restrict__ decb,
    const unsigned short* __restrict__ wEh, const unsigned short* __restrict__ wDh,
    float* __restrict__ out, unsigned int* __restrict__ counter,
    float* __restrict__ list)
{
  __shared__ __align__(16) unsigned char pool[70656];   // 2 blocks/CU limiter
  const int tid = threadIdx.x;
  const int w = tid >> 6, l = tid & 63;
  const int wr = w >> 2, wcg = w & 3;
  const int rbase = blockIdx.x * RPB;

  // x stage: thread -> (row = tid>>3, seg = tid&7), 4 consecutive floats
  const int srow = tid >> 3, seg = tid & 7;
  const float* gXc = x + (size_t)(rbase + srow) * DD + seg * 4;
  const int xwoff = srow * 80 + seg * 8;      // hi-plane byte offset (80B rows)

  // B DMA: thread copies 16B at tid*16 of each 8KB kstep plane
  const unsigned short* gE = wEh + (size_t)tid * 8;
  const unsigned short* gD = wDh + (size_t)tid * 8;
  const int dmadst = w * 1024;                // wave-uniform LDS base

  // A-fragment read offsets (80B-stride rows; kslot = l>>4)
  int rowb[2];
#pragma unroll
  for (int rt = 0; rt < 2; ++rt)
    rowb[rt] = (wr * 32 + rt * 16 + (l & 15)) * 80 + ((l >> 4) << 4);

  // B read offsets within a buffer (E plane @10240, D plane @18432)
  const int ebo = 10240 + wcg * 2048 + l * 16;

  f32x4 accE[2][2], accD[2][2];
  const f32x4 zero4 = {0.f, 0.f, 0.f, 0.f};
#pragma unroll
  for (int rt = 0; rt < 2; ++rt)
#pragma unroll
    for (int ct = 0; ct < 2; ++ct) { accE[rt][ct] = zero4; accD[rt][ct] = zero4; }

  auto DMAB = [&](int nb, int t) {
    gld16(gE + (size_t)t * 4096, pool + nb + 10240 + dmadst);
    gld16(gD + (size_t)t * 4096, pool + nb + 18432 + dmadst);
  };
  auto WRX = [&](int nb, f32x4 A) {
    unsigned u0 = __float_as_uint(A[0]);
    unsigned u1 = __float_as_uint(A[1]);
    unsigned u2 = __float_as_uint(A[2]);
    unsigned u3 = __float_as_uint(A[3]);
    u32x2 hi, lo;
    hi[0] = (u0 >> 16) | (u1 & 0xFFFF0000u);
    hi[1] = (u2 >> 16) | (u3 & 0xFFFF0000u);
    float r0 = A[0] - __uint_as_float(u0 & 0xFFFF0000u);
    float r1 = A[1] - __uint_as_float(u1 & 0xFFFF0000u);
    float r2 = A[2] - __uint_as_float(u2 & 0xFFFF0000u);
    float r3 = A[3] - __uint_as_float(u3 & 0xFFFF0000u);
    lo[0] = (__float_as_uint(r0) >> 16) | (__float_as_uint(r1) & 0xFFFF0000u);
    lo[1] = (__float_as_uint(r2) >> 16) | (__float_as_uint(r3) & 0xFFFF0000u);
    unsigned char* bp = pool + nb + xwoff;
    *(u32x2*)bp          = hi;
    *(u32x2*)(bp + 5120) = lo;
  };

#define MFMA(a, b, c) __builtin_amdgcn_mfma_f32_16x16x32_bf16(a, b, c, 0, 0, 0)
#define KSTEP(cb) do {                                                           \
    const unsigned char* bp = pool + (cb);                                       \
    bf16x8 E0 = *(const bf16x8*)(bp + ebo);                                      \
    bf16x8 E1 = *(const bf16x8*)(bp + ebo + 1024);                               \
    bf16x8 D0 = *(const bf16x8*)(bp + ebo + 8192);                               \
    bf16x8 D1 = *(const bf16x8*)(bp + ebo + 8192 + 1024);                        \
    _Pragma("unroll")                                                            \
    for (int rt = 0; rt < 2; ++rt) {                                             \
      bf16x8 ah = *(const bf16x8*)(bp + rowb[rt]);                               \
      bf16x8 al = *(const bf16x8*)(bp + rowb[rt] + 5120);                        \
      accE[rt][0] = MFMA(ah, E0, accE[rt][0]);                                   \
      accE[rt][1] = MFMA(ah, E1, accE[rt][1]);                                   \
      accD[rt][0] = MFMA(ah, D0, accD[rt][0]);                                   \
      accD[rt][1] = MFMA(ah, D1, accD[rt][1]);                                   \
      accE[rt][0] = MFMA(al, E0, accE[rt][0]);                                   \
      accE[rt][1] = MFMA(al, E1, accE[rt][1]);                                   \
    }                                                                            \
  } while (0)

  // prologue: kstep 0 -> buffer 0
  {
    f32x4 xA = *(const f32x4*)gXc;
    DMAB(0, 0);
    WRX(0, xA);
    asm volatile("s_waitcnt vmcnt(0) lgkmcnt(0)" ::: "memory");
    __builtin_amdgcn_s_barrier();
  }

  for (int t = 0; t < NT; ++t) {
    const int cb = (t & 1) * BUFS;
    const int nb = cb ^ BUFS;
    f32x4 xA;
    if (t + 1 < NT) {
      DMAB(nb, t + 1);                       // full-kstep head start
      xA = *(const f32x4*)(gXc + (size_t)(t + 1) * 32);
    }
    __builtin_amdgcn_s_setprio(1);
    KSTEP(cb);
    __builtin_amdgcn_s_setprio(0);
    if (t + 1 < NT) WRX(nb, xA);
    asm volatile("s_waitcnt vmcnt(0) lgkmcnt(0)" ::: "memory");
    __builtin_amdgcn_s_barrier();
  }
#undef KSTEP
#undef MFMA

  // ---------------- epilogue (overlays the staging pool) ----------------
  float* sT  = (float*)pool;                  // [64][132] dec-GEMM results
  float* sS  = (float*)(pool + 33792);        // [64][128] enc s-values (biased)
  float* sm1 = (float*)(pool + 66560);        // [64][4] top-1
  float* sm2 = (float*)(pool + 67584);        // [64][4] top-2
  int*   si1 = (int*)  (pool + 68608);        // [64][4] argmax col

  {
    const int q = l >> 4, cc = l & 15;
    const int col0 = wcg * 32 + cc;
    const int col1 = col0 + 16;
#pragma unroll
    for (int rt = 0; rt < 2; ++rt)
#pragma unroll
      for (int ct = 0; ct < 2; ++ct) {
        const int col = wcg * 32 + ct * 16 + cc;
#pragma unroll
        for (int i = 0; i < 4; ++i)
          sT[(wr * 32 + rt * 16 + q * 4 + i) * 132 + col] = accD[rt][ct][i];
      }
    const float b0 = encb[col0], b1 = encb[col1];
    float m1v[8], m2v[8]; int i1v[8];
#pragma unroll
    for (int rt = 0; rt < 2; ++rt)
#pragma unroll
      for (int i = 0; i < 4; ++i) {
        const int j = rt * 4 + i;
        const int row = wr * 32 + rt * 16 + q * 4 + i;
        float v0 = accE[rt][0][i] + b0;
        float v1 = accE[rt][1][i] + b1;
        sS[row * 128 + col0] = v0;
        sS[row * 128 + col1] = v1;
        if (v0 >= v1) { m1v[j] = v0; m2v[j] = v1; i1v[j] = col0; }
        else          { m1v[j] = v1; m2v[j] = v0; i1v[j] = col1; }
      }
#pragma unroll
    for (int d = 1; d < 16; d <<= 1) {
#pragma unroll
      for (int j = 0; j < 8; ++j) {
        float om1 = __shfl_xor(m1v[j], d);
        float om2 = __shfl_xor(m2v[j], d);
        int   oi  = __shfl_xor(i1v[j], d);
        if (om1 > m1v[j] || (om1 == m1v[j] && oi < i1v[j])) {
          m2v[j] = fmaxf(m1v[j], om2); m1v[j] = om1; i1v[j] = oi;
        } else {
          m2v[j] = fmaxf(m2v[j], om1);
        }
      }
    }
    if (cc == 0) {
#pragma unroll
      for (int rt = 0; rt < 2; ++rt)
#pragma unroll
        for (int i = 0; i < 4; ++i) {
          const int j = rt * 4 + i;
          const int row = wr * 32 + rt * 16 + q * 4 + i;
          sm1[row * 4 + wcg] = m1v[j];
          sm2[row * 4 + wcg] = m2v[j];
          si1[row * 4 + wcg] = i1v[j];
        }
    }
  }
  __syncthreads();

  float lossAcc = 0.f, accAcc = 0.f;
  if (tid < RPB) {
    const int row = tid, R = rbase + row;
    float m1 = -3.4e38f, m2 = -3.4e38f; int i1 = 0;
#pragma unroll
    for (int g = 0; g < 4; ++g) {
      float a1g = sm1[row * 4 + g], a2g = sm2[row * 4 + g];
      int ai = si1[row * 4 + g];
      if (a1g > m1) { m2 = fmaxf(m1, a2g); m1 = a1g; i1 = ai; }
      else          { m2 = fmaxf(m2, a1g); }
    }
    float yh = sT[row * 132 + i1] + decb[i1];
    out[R]      = yh;
    out[BB + R] = (float)i1;
    if (m1 - m2 < DELTA) {                     // near-tie: fp64 re-resolve later
      unsigned p = atomicAdd(counter, 1u);
      if (p < (unsigned)FCAP) {
        float* ent = list + (size_t)p * 132;
        ((unsigned*)ent)[0] = (unsigned)R;
        const f32x4* sr = (const f32x4*)(sS + row * 128);
        f32x4* dst = (f32x4*)(ent + 4);
#pragma unroll
        for (int j = 0; j < 32; ++j) dst[j] = sr[j];
      }
    }
    float yv = y[R];
    float d  = yh - yv;
    lossAcc = d * d;
    float sg = (yh > 0.f) ? 1.f : ((yh < 0.f) ? -1.f : 0.f);
    accAcc = (sg == yv) ? 1.f : 0.f;
  }
#pragma unroll
  for (int d = 1; d < 64; d <<= 1) {
    lossAcc += __shfl_xor(lossAcc, d);
    accAcc  += __shfl_xor(accAcc, d);
  }
  if (tid == 0) {
    atomicAdd(&out[2*BB],     lossAcc * (1.f / BB));
    atomicAdd(&out[2*BB + 1], accAcc  * (1.f / BB));
  }
}

// ---------------------------------------------------------------------------
// Fixup v2: one wave per flagged row. Reads the dumped approx s-row, selects
// candidate cols within (m1 - 2*DELTA), recomputes ONLY those (typically 1-3)
// in fp64 (coalesced 1KB loads), picks the true argmax, recomputes y_hat in
// fp64, patches out + loss/accuracy atomics.
// ---------------------------------------------------------------------------
__global__ __launch_bounds__(64) void fixup_kernel(
    const float* __restrict__ x, const float* __restrict__ y,
    const float* __restrict__ encW, const float* __restrict__ encb,
    const float* __restrict__ decW, const float* __restrict__ decb,
    float* __restrict__ out,
    const unsigned int* __restrict__ counter, const float* __restrict__ list)
{
  int n = (int)*counter;
  if (n > FCAP) n = FCAP;
  const int l = threadIdx.x;
  for (int e = blockIdx.x; e < n; e += gridDim.x) {
    const float* ent = list + (size_t)e * 132;
    const int R = (int)((const unsigned*)ent)[0];
    const float s0 = ent[4 + 2 * l], s1 = ent[5 + 2 * l];
    float m = fmaxf(s0, s1);
#pragma unroll
    for (int d = 1; d < 64; d <<= 1) m = fmaxf(m, __shfl_xor(m, d));
    const float win = m - 2.0f * DELTA;
    unsigned long long mm0 = __ballot(s0 >= win);
    unsigned long long mm1 = __ballot(s1 >= win);
    const float* xr = x + (size_t)R * DD;
    double best = -1e300; int bk = KK;
    while (mm0 | mm1) {
      int c;
      if (mm0) { int b = __builtin_ctzll(mm0); mm0 &= mm0 - 1; c = 2 * b; }
      else     { int b = __builtin_ctzll(mm1); mm1 &= mm1 - 1; c = 2 * b + 1; }
      const float* wp = encW + (size_t)c * DD;
      double s = 0.0;
#pragma unroll
      for (int j = 0; j < 8; ++j) {
        f32x4 wv = *(const f32x4*)(wp + j * 256 + l * 4);
        f32x4 xv = *(const f32x4*)(xr + j * 256 + l * 4);
        s = fma((double)xv[0], (double)wv[0], s);
        s = fma((double)xv[1], (double)wv[1], s);
        s = fma((double)xv[2], (double)wv[2], s);
        s = fma((double)xv[3], (double)wv[3], s);
      }
#pragma unroll
      for (int d = 1; d < 64; d <<= 1) s += __shfl_xor(s, d);
      s += (double)encb[c];
      if (s > best || (s == best && c < bk)) { best = s; bk = c; }
    }
    // dec dot in fp64
    const float* dr = decW + (size_t)bk * DD;
    double t = 0.0;
#pragma unroll
    for (int j = 0; j < 8; ++j) {
      f32x4 wv = *(const f32x4*)(dr + j * 256 + l * 4);
      f32x4 xv = *(const f32x4*)(xr + j * 256 + l * 4);
      t = fma((double)xv[0], (double)wv[0], t);
      t = fma((double)xv[1], (double)wv[1], t);
      t = fma((double)xv[2], (double)wv[2], t);
      t = fma((double)xv[3], (double)wv[3], t);
    }
#pragma unroll
    for (int d = 1; d < 64; d <<= 1) t += __shfl_xor(t, d);
    if (l == 0) {
      float yh = (float)(t + (double)decb[bk]);
      float yv = y[R];
      float old = out[R];
      float dn = yh - yv, dol = old - yv;
      atomicAdd(&out[2*BB], (dn*dn - dol*dol) * (1.f / BB));
      float sgn = (yh  > 0.f) ? 1.f : ((yh  < 0.f) ? -1.f : 0.f);
      float sgo = (old > 0.f) ? 1.f : ((old < 0.f) ? -1.f : 0.f);
      float mn = (sgn == yv) ? 1.f : 0.f;
      float mo = (sgo == yv) ? 1.f : 0.f;
      atomicAdd(&out[2*BB + 1], (mn - mo) * (1.f / BB));
      out[R]      = yh;
      out[BB + R] = (float)bk;
    }
  }
}

extern "C" void kernel_launch(void* const* d_in, const int* in_sizes, int n_in,
                              void* d_out, int out_size, void* d_ws, size_t ws_size,
                              hipStream_t stream)
{
  const float* x    = (const float*)d_in[0];
  const float* y    = (const float*)d_in[1];
  // d_in[2] = z (unused by the reference computation)
  const float* encW = (const float*)d_in[3];
  const float* encb = (const float*)d_in[4];
  const float* decW = (const float*)d_in[5];   // [1,128,2048] -> row-major [128][2048]
  const float* decb = (const float*)d_in[6];
  float* out = (float*)d_out;

  unsigned char* ws = (unsigned char*)d_ws;
  unsigned short* wEh = (unsigned short*)ws;                 // 512 KB
  unsigned short* wDh = (unsigned short*)(ws + 524288);      // 512 KB
  unsigned int* counter = (unsigned int*)(ws + 1048576);
  float* list = (float*)(ws + 1048592);                      // FCAP x 132 floats

  prep_kernel<<<128, 256, 0, stream>>>(encW, decW, wEh, wDh, out, counter);
  main_kernel<<<NBLK, 512, 0, stream>>>(x, y, encb, decb, wEh, wDh,
                                        out, counter, list);
  fixup_kernel<<<512, 64, 0, stream>>>(x, y, encW, encb, decW, decb,
                                       out, counter, list);
}